// Round 13
// baseline (129.381 us; speedup 1.0000x reference)
//
#include <hip/hip_runtime.h>
#include <stdint.h>

#define B_   2
#define S_   2048
#define D_   1024
#define H_   16
#define DH_  64
#define MTOK (B_*S_)   // 4096

typedef __attribute__((ext_vector_type(8))) short  short8v;
typedef __attribute__((ext_vector_type(4))) float  f32x4;
typedef __attribute__((ext_vector_type(16))) float f32x16;
typedef __attribute__((ext_vector_type(4))) unsigned int uint4v;

__device__ __forceinline__ unsigned short f2bf(float f) {
  unsigned int u = __builtin_bit_cast(unsigned int, f);
  unsigned int r = (u + 0x7fffu + ((u >> 16) & 1u)) >> 16;
  return (unsigned short)r;
}

__device__ __forceinline__ f32x4 zero4() { f32x4 v = {0.f, 0.f, 0.f, 0.f}; return v; }
__device__ __forceinline__ f32x16 zero16() {
  f32x16 v;
#pragma unroll
  for (int i = 0; i < 16; ++i) v[i] = 0.f;
  return v;
}

__device__ __forceinline__ unsigned int cvtpk(float lo, float hi) {
  unsigned int d;
  asm("v_cvt_pk_bf16_f32 %0, %1, %2" : "=v"(d) : "v"(lo), "v"(hi));
  return d;
}
// after: a = [a_low | b_low], b = [a_high | b_high]
// NOTE: permlane reads bypass VALU forwarding; only safe here because operands
// come from separate compiler-scheduled statements. Do NOT feed it a value
// written by an immediately-preceding instruction in the same asm block.
__device__ __forceinline__ void plswap(unsigned int& a, unsigned int& b) {
  asm("v_permlane32_swap_b32 %0, %1" : "+v"(a), "+v"(b));
}

__device__ __forceinline__ void gload16(const void* g, void* l) {
  __builtin_amdgcn_global_load_lds(
      (const __attribute__((address_space(1))) void*)g,
      (__attribute__((address_space(3))) void*)l, 16, 0, 0);
}

// ---------------- f32 -> bf16 conversion: x + 4 weights in ONE launch ----------
__global__ void cvt_all_kernel(
    const float* __restrict__ x,
    const float* __restrict__ w0, const float* __restrict__ w1,
    const float* __restrict__ w2, const float* __restrict__ w3,
    unsigned short* __restrict__ xb,
    unsigned short* __restrict__ o0, unsigned short* __restrict__ o1,
    unsigned short* __restrict__ o2, unsigned short* __restrict__ o3)
{
  int i = blockIdx.x * blockDim.x + threadIdx.x;   // 0 .. 2M-1 (float4 items)
  const float* in;
  unsigned short* out;
  int off;
  if (i < MTOK * D_ / 4) {            // 1048576 x-items
    in = x; out = xb; off = i;
  } else {
    int j = i - MTOK * D_ / 4;        // 262144 items per weight
    int w = j >> 18;
    off = j & 262143;
    in  = (w == 0) ? w0 : (w == 1) ? w1 : (w == 2) ? w2 : w3;
    out = (w == 0) ? o0 : (w == 1) ? o1 : (w == 2) ? o2 : o3;
  }
  float4 v = reinterpret_cast<const float4*>(in)[off];
  ushort4 o;
  o.x = f2bf(v.x); o.y = f2bf(v.y); o.z = f2bf(v.z); o.w = f2bf(v.w);
  reinterpret_cast<ushort4*>(out)[off] = o;
}

// ---------------- shared NT-GEMM mainloop: C = A((MI*32)xK) * Bt(128xK)^T ----
// r7 structure (verified r7/r10/r11/r12): BK=32 double-buffer, stage(k+1)
// issues into the other buffer while MFMA consumes k; vmcnt(0)+raw barrier
// after compute. Swizzle (row>>1)&3: bank-conflict-free (r11: 0).
// Templated on MI (A-frags per wave): MI=4 -> 128x128 tile (gemm_out),
// MI=8 -> 256x128 tile (qkv: 2x MFMA per k-step amortizes the fixed ~300-500
// cyc stage+drain overhead; r12 qkv was overhead-dominated at MfmaUtil 22%).
template <int MI>
__device__ __forceinline__ void stage_gemmT(
    const unsigned short* __restrict__ A, const unsigned short* __restrict__ Bt,
    int K, int m0, int n0, int k0, unsigned short* As, unsigned short* Bs, int tid)
{
#pragma unroll
  for (int it = 0; it < MI / 2; ++it) {   // A: MI*32 rows x 4 slots of 16B
    int fa = it * 256 + tid;
    int row = fa >> 2, slot = fa & 3;
    int gs = slot ^ ((row >> 1) & 3);
    gload16(A + (size_t)(m0 + row) * K + k0 + gs * 8, (char*)As + fa * 16);
  }
#pragma unroll
  for (int it = 0; it < 2; ++it) {        // B: 128 rows
    int fa = it * 256 + tid;
    int row = fa >> 2, slot = fa & 3;
    int gs = slot ^ ((row >> 1) & 3);
    gload16(Bt + (size_t)(n0 + row) * K + k0 + gs * 8, (char*)Bs + fa * 16);
  }
}

template <int MI>
__device__ __forceinline__ void gemm_mainloopT(
    const unsigned short* __restrict__ A, const unsigned short* __restrict__ Bt,
    int K, int m0, int n0, unsigned short* As, unsigned short* Bs, f32x4 acc[MI][4])
{
  const int ABUF = MI * 32 * 32;   // shorts per A buffer
  const int tid = threadIdx.x;
  const int lane = tid & 63, wid = tid >> 6;
  const int wr = wid >> 1, wc = wid & 1;
  const int l15 = lane & 15, g = lane >> 4;

#pragma unroll
  for (int mi = 0; mi < MI; ++mi)
#pragma unroll
    for (int ni = 0; ni < 4; ++ni) acc[mi][ni] = zero4();

  const int nk = K >> 5;   // BK=32
  stage_gemmT<MI>(A, Bt, K, m0, n0, 0, As, Bs, tid);
  asm volatile("s_waitcnt vmcnt(0)" ::: "memory");
  __builtin_amdgcn_s_barrier();
  asm volatile("" ::: "memory");

  for (int k = 0; k < nk; ++k) {
    if (k + 1 < nk)
      stage_gemmT<MI>(A, Bt, K, m0, n0, (k + 1) << 5,
                      As + ((k + 1) & 1) * ABUF, Bs + ((k + 1) & 1) * 4096, tid);
    const char* Ab = (const char*)(As + (k & 1) * ABUF);
    const char* Bb = (const char*)(Bs + (k & 1) * 4096);
    short8v af[MI], bfr[4];
#pragma unroll
    for (int mi = 0; mi < MI; ++mi) {
      int row = wr * (MI * 16) + mi * 16 + l15;
      int slot = g ^ ((row >> 1) & 3);
      af[mi] = *(const short8v*)(Ab + row * 64 + slot * 16);
    }
#pragma unroll
    for (int ni = 0; ni < 4; ++ni) {
      int row = wc * 64 + ni * 16 + l15;
      int slot = g ^ ((row >> 1) & 3);
      bfr[ni] = *(const short8v*)(Bb + row * 64 + slot * 16);
    }
#pragma unroll
    for (int mi = 0; mi < MI; ++mi)
#pragma unroll
      for (int ni = 0; ni < 4; ++ni)
        acc[mi][ni] = __builtin_amdgcn_mfma_f32_16x16x32_bf16(af[mi], bfr[ni], acc[mi][ni], 0, 0, 0);
    // counted-wait AFTER compute: stage(k+1) latency hidden under compute(k)
    asm volatile("s_waitcnt vmcnt(0)" ::: "memory");
    __builtin_amdgcn_s_barrier();
    asm volatile("" ::: "memory");
  }
}

// ---------------- fused QKV projection (256x128 tile, MI=8) ----------------
// z=0: Q*(1/sqrt(DH)*log2e) -> [B,H,S,DH]; z=1: K -> [B,H,S,DH]; z=2: V -> [B,H,DH,S]
// Flat 384-block grid, XCD-chunked: each XCD owns 2 M-tiles x 24 N-tiles
// (n-fastest, all 3 weight slices) for A-panel L2 reuse (r12 verified scheme).
__global__ __launch_bounds__(256, 2) void gemm_qkv_kernel(
    const unsigned short* __restrict__ xb,
    const unsigned short* __restrict__ wqb, const unsigned short* __restrict__ wkb,
    const unsigned short* __restrict__ wvb,
    const float* __restrict__ bq, const float* __restrict__ bk, const float* __restrict__ bv,
    unsigned short* __restrict__ Qb, unsigned short* __restrict__ Kb, unsigned short* __restrict__ VTb)
{
  __shared__ __align__(16) unsigned short As[2 * 256 * 32];  // 32KB
  __shared__ __align__(16) unsigned short Bs[2 * 128 * 32];  // 16KB
  const int flat = blockIdx.x;                 // 0..383
  const int xcd = flat & 7, off = flat >> 3;   // off 0..47
  const int mtile = xcd * 2 + (off / 24);      // 0..15 (bijective)
  const int ntile = off % 24;                  // 0..23
  const int z = ntile >> 3;
  const int m0 = mtile * 256, n0 = (ntile & 7) * 128;
  const unsigned short* Bt = (z == 0) ? wqb : (z == 1) ? wkb : wvb;
  const float* bias = (z == 0) ? bq : (z == 1) ? bk : bv;
  const float scl = (z == 0) ? 0.180336880f : 1.0f;  // 1/8 * log2(e)

  f32x4 acc[8][4];
  gemm_mainloopT<8>(xb, Bt, D_, m0, n0, As, Bs, acc);

  const int tid = threadIdx.x, lane = tid & 63, wid = tid >> 6;
  const int wr = wid >> 1, wc = wid & 1, l15 = lane & 15, g = lane >> 4;
#pragma unroll
  for (int ni = 0; ni < 4; ++ni) {
    int n = n0 + wc * 64 + ni * 16 + l15;
    float bia = bias[n];
    int hh = n >> 6, dh = n & 63;
#pragma unroll
    for (int mi = 0; mi < 8; ++mi) {
      int mbase = m0 + wr * 128 + mi * 16 + 4 * g;
      int b = mbase >> 11;
      int s0 = mbase & 2047;
      if (z < 2) {
        unsigned short* o = (z == 0) ? Qb : Kb;
#pragma unroll
        for (int r = 0; r < 4; ++r) {
          float v = (acc[mi][ni][r] + bia) * scl;
          o[(((size_t)(b * H_ + hh) * S_ + (s0 + r)) << 6) + dh] = f2bf(v);
        }
      } else {
        ushort4 o;
        o.x = f2bf(acc[mi][ni][0] + bia);
        o.y = f2bf(acc[mi][ni][1] + bia);
        o.z = f2bf(acc[mi][ni][2] + bia);
        o.w = f2bf(acc[mi][ni][3] + bia);
        *(ushort4*)(VTb + ((size_t)(b * H_ + hh) * DH_ + dh) * S_ + s0) = o;
      }
    }
  }
}

// ---------------- flash attention (causal, swapped-QK^T 32x32, split-K) ------
// QBLK=128, 512 threads = 8 waves: 4 q-waves x 2 KEY-GROUPS. Groups split
// WITHIN each staged 128-key tile (group kp owns keys kp*64..kp*64+63):
// LDS = 2 x 32KB = 64KB -> 2 blocks/CU (r10-r12 verified ~44us). End merge =
// associative online-softmax combine via LDS.
__device__ __forceinline__ void stage_tile128_w8(
    const unsigned short* Kh, const unsigned short* Vh, int t0, char* base, int tid)
{
  // K: 128 keys x 128B = 16KB, row=key, 8 slots of 16B, XOR-swizzled
#pragma unroll
  for (int it = 0; it < 2; ++it) {
    int fa = it * 512 + tid;
    int row = fa >> 3, slot = fa & 7, gs = slot ^ (row & 7);
    gload16(Kh + (size_t)(t0 + row) * DH_ + gs * 8, base + fa * 16);
  }
  // V^T: 64 d-rows x 256B (128 keys) = 16KB, 16 slots of 16B, low-3-bit XOR
#pragma unroll
  for (int it = 0; it < 2; ++it) {
    int fa = it * 512 + tid;
    int row = fa >> 4, slot = fa & 15;
    int gs = slot ^ (row & 7);
    gload16(Vh + (size_t)row * S_ + t0 + gs * 8, base + 16384 + fa * 16);
  }
}

__global__ __launch_bounds__(512, 4) void attn_kernel(
    const unsigned short* __restrict__ Qb, const unsigned short* __restrict__ Kb,
    const unsigned short* __restrict__ VTb, unsigned short* __restrict__ ctxb)
{
  __shared__ __align__(16) char smem[65536];  // 2 super-buffers x (K 16KB + V 16KB)
  const int tid = threadIdx.x, lane = tid & 63, wid = tid >> 6;  // wid 0..7
  const int qw = wid & 3, kp = wid >> 2;      // q-wave, key-group (sub in tile)
  const int l31 = lane & 31, h = lane >> 5;
  // XCD-aware flat-grid remap: fid%8 ~ XCD; give each XCD 4 heads (L2-fit)
  const int fid = blockIdx.x;
  const int bh = (fid & 7) * 4 + ((fid >> 3) & 3);
  const int qpos = fid >> 5;
  const int qi = (qpos < 8) ? qpos : 23 - qpos;  // pairs (p,15-p) per CU
  const int qblk = qi * 128;
  const int q0w = qblk + qw * 32;
  const int qg = q0w + l31;
  const unsigned short* Qh = Qb + (size_t)bh * S_ * DH_;
  const unsigned short* Kh = Kb + (size_t)bh * S_ * DH_;
  const unsigned short* Vh = VTb + (size_t)bh * DH_ * S_;

  // Q B-fragments: col=q=l31, k(dh) = 16*kk + 8*h + e  (Q pre-scaled in QKV epilogue)
  short8v qf[4];
#pragma unroll
  for (int kk = 0; kk < 4; ++kk)
    qf[kk] = *(const short8v*)(Qh + (size_t)qg * DH_ + kk * 16 + h * 8);

  f32x16 ctx0 = zero16(), ctx1 = zero16();
  float mrun = -3e38f, lrun = 0.f;

  const int nt = qi + 1;            // 128-key tiles 0..qi

  stage_tile128_w8(Kh, Vh, 0, smem, tid);
  asm volatile("s_waitcnt vmcnt(0)" ::: "memory");
  __builtin_amdgcn_s_barrier();
  asm volatile("" ::: "memory");

  for (int t = 0; t < nt; ++t) {
    if (t + 1 < nt) stage_tile128_w8(Kh, Vh, (t + 1) << 7, smem + (((t + 1) & 1) * 32768), tid);
    const char* Kbuf = smem + (t & 1) * 32768;
    const char* Vbuf = Kbuf + 16384;
    const int t0 = (t << 7) + (kp << 6);   // this group's 64-key subtile
    if (t0 <= q0w + 31) {                  // within this wave's causal range
      const char* Kt = Kbuf + kp * 8192;

      // QK^T swapped: s = mfma(A=K, B=Q) -> S^T[key][q], col=q=l31
      f32x16 s0 = zero16(), s1 = zero16();
      __builtin_amdgcn_s_setprio(1);
#pragma unroll
      for (int kk = 0; kk < 4; ++kk) {
        int slot = (2 * kk + h) ^ (l31 & 7);
        short8v kf0 = *(const short8v*)(Kt + l31 * 128 + slot * 16);
        short8v kf1 = *(const short8v*)(Kt + (32 + l31) * 128 + slot * 16);
        s0 = __builtin_amdgcn_mfma_f32_32x32x16_bf16(kf0, qf[kk], s0, 0, 0, 0);
        s1 = __builtin_amdgcn_mfma_f32_32x32x16_bf16(kf1, qf[kk], s1, 0, 0, 0);
      }
      __builtin_amdgcn_s_setprio(0);
      // causal mask when tile overlaps any diagonal of this wave
      if (t0 + 63 > q0w) {
#pragma unroll
        for (int r = 0; r < 16; ++r) {
          int k0i = (r & 3) + 8 * (r >> 2) + 4 * h;
          if (t0 + k0i > qg) s0[r] = -1e30f;
          if (t0 + k0i + 32 > qg) s1[r] = -1e30f;
        }
      }
      // lane-local row max: tree, then cross-half combine via shfl_xor(32)
      float tm;
      {
        float m01[8];
#pragma unroll
        for (int r = 0; r < 8; ++r)
          m01[r] = fmaxf(fmaxf(s0[r], s0[r + 8]), fmaxf(s1[r], s1[r + 8]));
        float a = fmaxf(fmaxf(m01[0], m01[1]), fmaxf(m01[2], m01[3]));
        float b = fmaxf(fmaxf(m01[4], m01[5]), fmaxf(m01[6], m01[7]));
        tm = fmaxf(a, b);
      }
      tm = fmaxf(tm, __shfl_xor(tm, 32));

      // defer-max: rescale only when tile max exceeds threshold (2^8 headroom)
      if (!__all(tm <= mrun + 8.f)) {
        float mnew = fmaxf(mrun, tm);
        float al = exp2f(mrun - mnew);
#pragma unroll
        for (int r = 0; r < 16; ++r) { ctx0[r] *= al; ctx1[r] *= al; }
        lrun *= al;
        mrun = mnew;
      }
      // P = 2^(s - mrun); 4-way partial row sums
      float p[32];
      float psa0 = 0.f, psa1 = 0.f, psa2 = 0.f, psa3 = 0.f;
#pragma unroll
      for (int r = 0; r < 16; r += 4) {
        p[r + 0] = exp2f(s0[r + 0] - mrun); psa0 += p[r + 0];
        p[r + 1] = exp2f(s0[r + 1] - mrun); psa1 += p[r + 1];
        p[r + 2] = exp2f(s0[r + 2] - mrun); psa2 += p[r + 2];
        p[r + 3] = exp2f(s0[r + 3] - mrun); psa3 += p[r + 3];
      }
#pragma unroll
      for (int r = 0; r < 16; r += 4) {
        p[16 + r + 0] = exp2f(s1[r + 0] - mrun); psa0 += p[16 + r + 0];
        p[16 + r + 1] = exp2f(s1[r + 1] - mrun); psa1 += p[16 + r + 1];
        p[16 + r + 2] = exp2f(s1[r + 2] - mrun); psa2 += p[16 + r + 2];
        p[16 + r + 3] = exp2f(s1[r + 3] - mrun); psa3 += p[16 + r + 3];
      }
      float ps = (psa0 + psa1) + (psa2 + psa3);
      ps += __shfl_xor(ps, 32);
      lrun += ps;

      unsigned int pk[16];
#pragma unroll
      for (int m = 0; m < 16; ++m) pk[m] = cvtpk(p[2 * m], p[2 * m + 1]);
#pragma unroll
      for (int base = 0; base < 16; base += 4) {
        plswap(pk[base + 0], pk[base + 2]);
        plswap(pk[base + 1], pk[base + 3]);
      }
      // PV: ctx^T[d][q] += V^T x P^T ; A=V^T frag row=d, 256B rows, +kp*128
      __builtin_amdgcn_s_setprio(1);
#pragma unroll
      for (int dt = 0; dt < 2; ++dt) {
        int row = dt * 32 + l31;
#pragma unroll
        for (int kt = 0; kt < 4; ++kt) {
          int slot = (2 * kt + h) ^ (row & 7);
          short8v vf = *(const short8v*)(Vbuf + row * 256 + kp * 128 + slot * 16);
          uint4v u = {pk[4 * kt], pk[4 * kt + 1], pk[4 * kt + 2], pk[4 * kt + 3]};
          short8v pf = __builtin_bit_cast(short8v, u);
          if (dt == 0) ctx0 = __builtin_amdgcn_mfma_f32_32x32x16_bf16(vf, pf, ctx0, 0, 0, 0);
          else         ctx1 = __builtin_amdgcn_mfma_f32_32x32x16_bf16(vf, pf, ctx1, 0, 0, 0);
        }
      }
      __builtin_amdgcn_s_setprio(0);
    }
    // counted-wait barrier AFTER compute: stage(t+1) latency hidden under compute(t)
    asm volatile("s_waitcnt vmcnt(0)" ::: "memory");
    __builtin_amdgcn_s_barrier();
    asm volatile("" ::: "memory");
  }

  // ---- split-K combine: group 1 publishes (ctx,m,l) via LDS; group 0 merges ----
  float* cws = (float*)smem + qw * 2176;   // 34 x 64 floats per q-wave (34KB total)
  if (kp == 1) {
#pragma unroll
    for (int r = 0; r < 16; ++r) {
      cws[r * 64 + lane]        = ctx0[r];
      cws[(16 + r) * 64 + lane] = ctx1[r];
    }
    cws[32 * 64 + lane] = mrun;
    cws[33 * 64 + lane] = lrun;
  }
  __syncthreads();
  if (kp == 0) {
    float pm = cws[32 * 64 + lane], pl = cws[33 * 64 + lane];
    float m  = fmaxf(mrun, pm);
    float sa = exp2f(mrun - m), sb = exp2f(pm - m);   // empty partner: sb = 0
    float L  = lrun * sa + pl * sb;
    float cf[32];
#pragma unroll
    for (int r = 0; r < 16; ++r) {
      cf[r]      = ctx0[r] * sa + cws[r * 64 + lane] * sb;
      cf[16 + r] = ctx1[r] * sa + cws[(16 + r) * 64 + lane] * sb;
    }
    const int b = bh >> 4, hcol = (bh & 15) * 64;
    unsigned short* orow = ctxb + (((size_t)(b * S_ + qg)) << 10) + hcol;
    float invL = 1.0f / L;
#pragma unroll
    for (int j = 0; j < 8; ++j) {
      uint2 w;
      w.x = cvtpk(cf[4 * j + 0] * invL, cf[4 * j + 1] * invL);
      w.y = cvtpk(cf[4 * j + 2] * invL, cf[4 * j + 3] * invL);
      // flat f=4j -> d = 32*(j>>2) + 8*(j&3) + 4*h
      *(uint2*)(orow + 32 * (j >> 2) + 8 * (j & 3) + 4 * h) = w;
    }
  }
}

// ---------------- output projection + bias + residual (fp32 y into d_out) ----------------
// Flat 256-block grid, XCD-chunked (4 M-tiles x 8 N-tiles per XCD), MI=4.
__global__ __launch_bounds__(256) void gemm_out_kernel(
    const unsigned short* __restrict__ ctxb, const unsigned short* __restrict__ wob,
    const float* __restrict__ bo, const float* __restrict__ x, float* __restrict__ y)
{
  __shared__ __align__(16) unsigned short As[2 * 128 * 32];
  __shared__ __align__(16) unsigned short Bs[2 * 128 * 32];
  const int flat = blockIdx.x;                 // 0..255
  const int xcd = flat & 7, off = flat >> 3;   // off 0..31
  const int m0 = (xcd * 4 + (off >> 3)) * 128; // bijective over 32 M-tiles
  const int n0 = (off & 7) * 128;
  f32x4 acc[4][4];
  gemm_mainloopT<4>(ctxb, wob, D_, m0, n0, As, Bs, acc);

  const int tid = threadIdx.x, lane = tid & 63, wid = tid >> 6;
  const int wr = wid >> 1, wc = wid & 1, l15 = lane & 15, g = lane >> 4;
#pragma unroll
  for (int ni = 0; ni < 4; ++ni) {
    int n = n0 + wc * 64 + ni * 16 + l15;
    float bia = bo[n];
#pragma unroll
    for (int mi = 0; mi < 4; ++mi) {
      int mbase = m0 + wr * 64 + mi * 16 + 4 * g;
#pragma unroll
      for (int r = 0; r < 4; ++r) {
        size_t idx = ((size_t)(mbase + r) << 10) + n;
        y[idx] = acc[mi][ni][r] + bia + x[idx];
      }
    }
  }
}

// ---------------- in-place LayerNorm over rows of d_out ----------------
__global__ __launch_bounds__(256) void ln_kernel(
    float* __restrict__ y, const float* __restrict__ gw, const float* __restrict__ bw)
{
  const int row = blockIdx.x;
  float* p = y + ((size_t)row << 10);
  const int t = threadIdx.x;
  float4 v = *(const float4*)(p + t * 4);
  float s  = v.x + v.y + v.z + v.w;
  float s2 = v.x * v.x + v.y * v.y + v.z * v.z + v.w * v.w;
#pragma unroll
  for (int d = 1; d < 64; d <<= 1) { s += __shfl_xor(s, d); s2 += __shfl_xor(s2, d); }
  __shared__ float ps[4], ps2[4];
  const int lane = t & 63, wid = t >> 6;
  if (lane == 0) { ps[wid] = s; ps2[wid] = s2; }
  __syncthreads();
  s  = ps[0] + ps[1] + ps[2] + ps[3];
  s2 = ps2[0] + ps2[1] + ps2[2] + ps2[3];
  float mu  = s * (1.f / 1024.f);
  float var = s2 * (1.f / 1024.f) - mu * mu;
  float rstd = rsqrtf(var + 1e-5f);
  float4 gv = *(const float4*)(gw + t * 4);
  float4 bv = *(const float4*)(bw + t * 4);
  float4 o;
  o.x = (v.x - mu) * rstd * gv.x + bv.x;
  o.y = (v.y - mu) * rstd * gv.y + bv.y;
  o.z = (v.z - mu) * rstd * gv.z + bv.z;
  o.w = (v.w - mu) * rstd * gv.w + bv.w;
  *(float4*)(p + t * 4) = o;
}

extern "C" void kernel_launch(void* const* d_in, const int* in_sizes, int n_in,
                              void* d_out, int out_size, void* d_ws, size_t ws_size,
                              hipStream_t stream) {
  const float* x   = (const float*)d_in[0];
  const float* Wq  = (const float*)d_in[1];
  const float* bq  = (const float*)d_in[2];
  const float* Wk  = (const float*)d_in[3];
  const float* bk  = (const float*)d_in[4];
  const float* Wv  = (const float*)d_in[5];
  const float* bv  = (const float*)d_in[6];
  const float* Wo  = (const float*)d_in[7];
  const float* bo  = (const float*)d_in[8];
  const float* lng = (const float*)d_in[9];
  const float* lnb = (const float*)d_in[10];
  float* out = (float*)d_out;

  char* ws = (char*)d_ws;
  unsigned short* xb  = (unsigned short*)ws;                 ws += (size_t)MTOK * D_ * 2;
  unsigned short* wqb = (unsigned short*)ws;                 ws += (size_t)D_ * D_ * 2;
  unsigned short* wkb = (unsigned short*)ws;                 ws += (size_t)D_ * D_ * 2;
  unsigned short* wvb = (unsigned short*)ws;                 ws += (size_t)D_ * D_ * 2;
  unsigned short* wob = (unsigned short*)ws;                 ws += (size_t)D_ * D_ * 2;
  unsigned short* Qb  = (unsigned short*)ws;                 ws += (size_t)B_ * H_ * S_ * DH_ * 2;
  unsigned short* Kb  = (unsigned short*)ws;                 ws += (size_t)B_ * H_ * S_ * DH_ * 2;
  unsigned short* VTb = (unsigned short*)ws;                 ws += (size_t)B_ * H_ * DH_ * S_ * 2;
  unsigned short* ctxb = (unsigned short*)ws;                ws += (size_t)MTOK * D_ * 2;

  // one conversion launch: x (1M float4) + 4 weights (4 x 256K float4)
  cvt_all_kernel<<<(MTOK * D_ / 4 + 4 * D_ * D_ / 4) / 256, 256, 0, stream>>>(
      x, Wq, Wk, Wv, Wo, xb, wqb, wkb, wvb, wob);

  // QKV: flat 384-block grid (256x128 tiles), XCD-chunked for A-panel L2 reuse
  gemm_qkv_kernel<<<dim3(384), 256, 0, stream>>>(
      xb, wqb, wkb, wvb, bq, bk, bv, Qb, Kb, VTb);

  // flash attention: 512 x 512-thread blocks, split-K within tile, 2 blocks/CU
  attn_kernel<<<dim3((S_ / 128) * B_ * H_), 512, 0, stream>>>(Qb, Kb, VTb, ctxb);

  // out-proj: flat 256-block grid, XCD-chunked
  gemm_out_kernel<<<dim3(256), 256, 0, stream>>>(ctxb, wob, bo, x, out);

  ln_kernel<<<MTOK, 256, 0, stream>>>(out, lng, lnb);
}

// Round 14
// 123.030 us; speedup vs baseline: 1.0516x; 1.0516x over previous
//
#include <hip/hip_runtime.h>
#include <stdint.h>

#define B_   2
#define S_   2048
#define D_   1024
#define H_   16
#define DH_  64
#define MTOK (B_*S_)   // 4096

typedef __attribute__((ext_vector_type(8))) short  short8v;
typedef __attribute__((ext_vector_type(4))) float  f32x4;
typedef __attribute__((ext_vector_type(16))) float f32x16;
typedef __attribute__((ext_vector_type(4))) unsigned int uint4v;

__device__ __forceinline__ unsigned short f2bf(float f) {
  unsigned int u = __builtin_bit_cast(unsigned int, f);
  unsigned int r = (u + 0x7fffu + ((u >> 16) & 1u)) >> 16;
  return (unsigned short)r;
}

__device__ __forceinline__ f32x4 zero4() { f32x4 v = {0.f, 0.f, 0.f, 0.f}; return v; }
__device__ __forceinline__ f32x16 zero16() {
  f32x16 v;
#pragma unroll
  for (int i = 0; i < 16; ++i) v[i] = 0.f;
  return v;
}

__device__ __forceinline__ unsigned int cvtpk(float lo, float hi) {
  unsigned int d;
  asm("v_cvt_pk_bf16_f32 %0, %1, %2" : "=v"(d) : "v"(lo), "v"(hi));
  return d;
}
// after: a = [a_low | b_low], b = [a_high | b_high]
// NOTE: permlane reads bypass VALU forwarding; only safe here because operands
// come from separate compiler-scheduled statements. Do NOT feed it a value
// written by an immediately-preceding instruction in the same asm block.
__device__ __forceinline__ void plswap(unsigned int& a, unsigned int& b) {
  asm("v_permlane32_swap_b32 %0, %1" : "+v"(a), "+v"(b));
}

__device__ __forceinline__ void gload16(const void* g, void* l) {
  __builtin_amdgcn_global_load_lds(
      (const __attribute__((address_space(1))) void*)g,
      (__attribute__((address_space(3))) void*)l, 16, 0, 0);
}

// ---------------- f32 -> bf16 conversion: x + 4 weights in ONE launch ----------
__global__ void cvt_all_kernel(
    const float* __restrict__ x,
    const float* __restrict__ w0, const float* __restrict__ w1,
    const float* __restrict__ w2, const float* __restrict__ w3,
    unsigned short* __restrict__ xb,
    unsigned short* __restrict__ o0, unsigned short* __restrict__ o1,
    unsigned short* __restrict__ o2, unsigned short* __restrict__ o3)
{
  int i = blockIdx.x * blockDim.x + threadIdx.x;   // 0 .. 2M-1 (float4 items)
  const float* in;
  unsigned short* out;
  int off;
  if (i < MTOK * D_ / 4) {            // 1048576 x-items
    in = x; out = xb; off = i;
  } else {
    int j = i - MTOK * D_ / 4;        // 262144 items per weight
    int w = j >> 18;
    off = j & 262143;
    in  = (w == 0) ? w0 : (w == 1) ? w1 : (w == 2) ? w2 : w3;
    out = (w == 0) ? o0 : (w == 1) ? o1 : (w == 2) ? o2 : o3;
  }
  float4 v = reinterpret_cast<const float4*>(in)[off];
  ushort4 o;
  o.x = f2bf(v.x); o.y = f2bf(v.y); o.z = f2bf(v.z); o.w = f2bf(v.w);
  reinterpret_cast<ushort4*>(out)[off] = o;
}

// ---------------- shared NT-GEMM mainloop: C = A(MxK) * Bt(NxK)^T ----------------
// r7 structure: BK=32 double-buffer, 2 x (8KB A + 8KB B) = 32KB -> 3 blocks/CU.
// stage(k+1) issues into the other 8KB pair while MFMA consumes k; vmcnt(0)+
// raw barrier after compute. Swizzle (row>>1)&3: bank-conflict-free (r11: 0).
// (r13 lesson: 256x128 tile -> 1.5 blocks/CU, drain unabsorbed, REGRESSED;
//  128^2 @ 3 blocks/CU is the robust optimum for this 2-barrier structure.)
__device__ __forceinline__ void stage_gemm32(
    const unsigned short* __restrict__ A, const unsigned short* __restrict__ Bt,
    int K, int m0, int n0, int k0, unsigned short* As, unsigned short* Bs, int tid)
{
#pragma unroll
  for (int it = 0; it < 2; ++it) {
    int fa = it * 256 + tid;           // 0..511: 128 rows x 4 slots of 16B
    int row = fa >> 2, slot = fa & 3;
    int gs = slot ^ ((row >> 1) & 3);
    gload16(A + (size_t)(m0 + row) * K + k0 + gs * 8, (char*)As + fa * 16);
  }
#pragma unroll
  for (int it = 0; it < 2; ++it) {
    int fa = it * 256 + tid;
    int row = fa >> 2, slot = fa & 3;
    int gs = slot ^ ((row >> 1) & 3);
    gload16(Bt + (size_t)(n0 + row) * K + k0 + gs * 8, (char*)Bs + fa * 16);
  }
}

__device__ __forceinline__ void gemm_mainloop(
    const unsigned short* __restrict__ A, const unsigned short* __restrict__ Bt,
    int K, int m0, int n0, unsigned short* As, unsigned short* Bs, f32x4 acc[4][4])
{
  const int tid = threadIdx.x;
  const int lane = tid & 63, wid = tid >> 6;
  const int wr = wid >> 1, wc = wid & 1;
  const int l15 = lane & 15, g = lane >> 4;

#pragma unroll
  for (int mi = 0; mi < 4; ++mi)
#pragma unroll
    for (int ni = 0; ni < 4; ++ni) acc[mi][ni] = zero4();

  const int nk = K >> 5;   // BK=32
  stage_gemm32(A, Bt, K, m0, n0, 0, As, Bs, tid);
  asm volatile("s_waitcnt vmcnt(0)" ::: "memory");
  __builtin_amdgcn_s_barrier();
  asm volatile("" ::: "memory");

  for (int k = 0; k < nk; ++k) {
    if (k + 1 < nk)
      stage_gemm32(A, Bt, K, m0, n0, (k + 1) << 5,
                   As + ((k + 1) & 1) * 4096, Bs + ((k + 1) & 1) * 4096, tid);
    const char* Ab = (const char*)(As + (k & 1) * 4096);
    const char* Bb = (const char*)(Bs + (k & 1) * 4096);
    short8v af[4], bfr[4];
#pragma unroll
    for (int mi = 0; mi < 4; ++mi) {
      int row = wr * 64 + mi * 16 + l15;
      int slot = g ^ ((row >> 1) & 3);
      af[mi] = *(const short8v*)(Ab + row * 64 + slot * 16);
    }
#pragma unroll
    for (int ni = 0; ni < 4; ++ni) {
      int row = wc * 64 + ni * 16 + l15;
      int slot = g ^ ((row >> 1) & 3);
      bfr[ni] = *(const short8v*)(Bb + row * 64 + slot * 16);
    }
#pragma unroll
    for (int mi = 0; mi < 4; ++mi)
#pragma unroll
      for (int ni = 0; ni < 4; ++ni)
        acc[mi][ni] = __builtin_amdgcn_mfma_f32_16x16x32_bf16(af[mi], bfr[ni], acc[mi][ni], 0, 0, 0);
    // counted-wait AFTER compute: stage(k+1) latency hidden under compute(k)
    asm volatile("s_waitcnt vmcnt(0)" ::: "memory");
    __builtin_amdgcn_s_barrier();
    asm volatile("" ::: "memory");
  }
}

// ---------------- fused QKV projection ----------------
// z=0: Q*(1/sqrt(DH)*log2e) -> [B,H,S,DH]; z=1: K -> [B,H,S,DH]; z=2: V -> [B,H,DH,S]
// Flat 768-block grid, XCD-chunked: each XCD owns 4 M-tiles x 24 N-tiles
// (n-fastest, all 3 weight slices) -> 24 consecutive co-resident blocks per
// XCD share one 256KB A-tile in that XCD's private L2 (r12 verified).
__global__ __launch_bounds__(256) void gemm_qkv_kernel(
    const unsigned short* __restrict__ xb,
    const unsigned short* __restrict__ wqb, const unsigned short* __restrict__ wkb,
    const unsigned short* __restrict__ wvb,
    const float* __restrict__ bq, const float* __restrict__ bk, const float* __restrict__ bv,
    unsigned short* __restrict__ Qb, unsigned short* __restrict__ Kb, unsigned short* __restrict__ VTb)
{
  __shared__ __align__(16) unsigned short As[2 * 128 * 32];  // 16KB
  __shared__ __align__(16) unsigned short Bs[2 * 128 * 32];  // 16KB
  const int flat = blockIdx.x;                 // 0..767
  const int xcd = flat & 7, off = flat >> 3;   // off 0..95
  const int mtile = xcd * 4 + (off / 24);      // 0..31 (bijective)
  const int ntile = off % 24;                  // 0..23
  const int z = ntile >> 3;
  const int m0 = mtile * 128, n0 = (ntile & 7) * 128;
  const unsigned short* Bt = (z == 0) ? wqb : (z == 1) ? wkb : wvb;
  const float* bias = (z == 0) ? bq : (z == 1) ? bk : bv;
  const float scl = (z == 0) ? 0.180336880f : 1.0f;  // 1/8 * log2(e)

  f32x4 acc[4][4];
  gemm_mainloop(xb, Bt, D_, m0, n0, As, Bs, acc);

  const int tid = threadIdx.x, lane = tid & 63, wid = tid >> 6;
  const int wr = wid >> 1, wc = wid & 1, l15 = lane & 15, g = lane >> 4;
#pragma unroll
  for (int ni = 0; ni < 4; ++ni) {
    int n = n0 + wc * 64 + ni * 16 + l15;
    float bia = bias[n];
    int hh = n >> 6, dh = n & 63;
#pragma unroll
    for (int mi = 0; mi < 4; ++mi) {
      int mbase = m0 + wr * 64 + mi * 16 + 4 * g;
      int b = mbase >> 11;
      int s0 = mbase & 2047;
      if (z < 2) {
        unsigned short* o = (z == 0) ? Qb : Kb;
#pragma unroll
        for (int r = 0; r < 4; ++r) {
          float v = (acc[mi][ni][r] + bia) * scl;
          o[(((size_t)(b * H_ + hh) * S_ + (s0 + r)) << 6) + dh] = f2bf(v);
        }
      } else {
        ushort4 o;
        o.x = f2bf(acc[mi][ni][0] + bia);
        o.y = f2bf(acc[mi][ni][1] + bia);
        o.z = f2bf(acc[mi][ni][2] + bia);
        o.w = f2bf(acc[mi][ni][3] + bia);
        *(ushort4*)(VTb + ((size_t)(b * H_ + hh) * DH_ + dh) * S_ + s0) = o;
      }
    }
  }
}

// ---------------- flash attention (causal, swapped-QK^T 32x32, split-K) ------
// QBLK=128, 512 threads = 8 waves: 4 q-waves x 2 KEY-GROUPS. Groups split
// WITHIN each staged 128-key tile (group kp owns keys kp*64..kp*64+63):
// LDS = 2 x 32KB = 64KB -> 2 blocks/CU (r10-r12 verified ~44us). End merge =
// associative online-softmax combine via LDS.
__device__ __forceinline__ void stage_tile128_w8(
    const unsigned short* Kh, const unsigned short* Vh, int t0, char* base, int tid)
{
  // K: 128 keys x 128B = 16KB, row=key, 8 slots of 16B, XOR-swizzled
#pragma unroll
  for (int it = 0; it < 2; ++it) {
    int fa = it * 512 + tid;
    int row = fa >> 3, slot = fa & 7, gs = slot ^ (row & 7);
    gload16(Kh + (size_t)(t0 + row) * DH_ + gs * 8, base + fa * 16);
  }
  // V^T: 64 d-rows x 256B (128 keys) = 16KB, 16 slots of 16B, low-3-bit XOR
#pragma unroll
  for (int it = 0; it < 2; ++it) {
    int fa = it * 512 + tid;
    int row = fa >> 4, slot = fa & 15;
    int gs = slot ^ (row & 7);
    gload16(Vh + (size_t)row * S_ + t0 + gs * 8, base + 16384 + fa * 16);
  }
}

__global__ __launch_bounds__(512, 4) void attn_kernel(
    const unsigned short* __restrict__ Qb, const unsigned short* __restrict__ Kb,
    const unsigned short* __restrict__ VTb, unsigned short* __restrict__ ctxb)
{
  __shared__ __align__(16) char smem[65536];  // 2 super-buffers x (K 16KB + V 16KB)
  const int tid = threadIdx.x, lane = tid & 63, wid = tid >> 6;  // wid 0..7
  const int qw = wid & 3, kp = wid >> 2;      // q-wave, key-group (sub in tile)
  const int l31 = lane & 31, h = lane >> 5;
  // XCD-aware flat-grid remap: fid%8 ~ XCD; give each XCD 4 heads (L2-fit)
  const int fid = blockIdx.x;
  const int bh = (fid & 7) * 4 + ((fid >> 3) & 3);
  const int qpos = fid >> 5;
  const int qi = (qpos < 8) ? qpos : 23 - qpos;  // pairs (p,15-p) per CU
  const int qblk = qi * 128;
  const int q0w = qblk + qw * 32;
  const int qg = q0w + l31;
  const unsigned short* Qh = Qb + (size_t)bh * S_ * DH_;
  const unsigned short* Kh = Kb + (size_t)bh * S_ * DH_;
  const unsigned short* Vh = VTb + (size_t)bh * DH_ * S_;

  // Q B-fragments: col=q=l31, k(dh) = 16*kk + 8*h + e  (Q pre-scaled in QKV epilogue)
  short8v qf[4];
#pragma unroll
  for (int kk = 0; kk < 4; ++kk)
    qf[kk] = *(const short8v*)(Qh + (size_t)qg * DH_ + kk * 16 + h * 8);

  f32x16 ctx0 = zero16(), ctx1 = zero16();
  float mrun = -3e38f, lrun = 0.f;

  const int nt = qi + 1;            // 128-key tiles 0..qi

  stage_tile128_w8(Kh, Vh, 0, smem, tid);
  asm volatile("s_waitcnt vmcnt(0)" ::: "memory");
  __builtin_amdgcn_s_barrier();
  asm volatile("" ::: "memory");

  for (int t = 0; t < nt; ++t) {
    if (t + 1 < nt) stage_tile128_w8(Kh, Vh, (t + 1) << 7, smem + (((t + 1) & 1) * 32768), tid);
    const char* Kbuf = smem + (t & 1) * 32768;
    const char* Vbuf = Kbuf + 16384;
    const int t0 = (t << 7) + (kp << 6);   // this group's 64-key subtile
    if (t0 <= q0w + 31) {                  // within this wave's causal range
      const char* Kt = Kbuf + kp * 8192;

      // QK^T swapped: s = mfma(A=K, B=Q) -> S^T[key][q], col=q=l31
      f32x16 s0 = zero16(), s1 = zero16();
      __builtin_amdgcn_s_setprio(1);
#pragma unroll
      for (int kk = 0; kk < 4; ++kk) {
        int slot = (2 * kk + h) ^ (l31 & 7);
        short8v kf0 = *(const short8v*)(Kt + l31 * 128 + slot * 16);
        short8v kf1 = *(const short8v*)(Kt + (32 + l31) * 128 + slot * 16);
        s0 = __builtin_amdgcn_mfma_f32_32x32x16_bf16(kf0, qf[kk], s0, 0, 0, 0);
        s1 = __builtin_amdgcn_mfma_f32_32x32x16_bf16(kf1, qf[kk], s1, 0, 0, 0);
      }
      __builtin_amdgcn_s_setprio(0);
      // causal mask when tile overlaps any diagonal of this wave
      if (t0 + 63 > q0w) {
#pragma unroll
        for (int r = 0; r < 16; ++r) {
          int k0i = (r & 3) + 8 * (r >> 2) + 4 * h;
          if (t0 + k0i > qg) s0[r] = -1e30f;
          if (t0 + k0i + 32 > qg) s1[r] = -1e30f;
        }
      }
      // lane-local row max: tree, then cross-half combine via shfl_xor(32)
      float tm;
      {
        float m01[8];
#pragma unroll
        for (int r = 0; r < 8; ++r)
          m01[r] = fmaxf(fmaxf(s0[r], s0[r + 8]), fmaxf(s1[r], s1[r + 8]));
        float a = fmaxf(fmaxf(m01[0], m01[1]), fmaxf(m01[2], m01[3]));
        float b = fmaxf(fmaxf(m01[4], m01[5]), fmaxf(m01[6], m01[7]));
        tm = fmaxf(a, b);
      }
      tm = fmaxf(tm, __shfl_xor(tm, 32));

      // defer-max: rescale only when tile max exceeds threshold (2^8 headroom)
      if (!__all(tm <= mrun + 8.f)) {
        float mnew = fmaxf(mrun, tm);
        float al = exp2f(mrun - mnew);
#pragma unroll
        for (int r = 0; r < 16; ++r) { ctx0[r] *= al; ctx1[r] *= al; }
        lrun *= al;
        mrun = mnew;
      }
      // P = 2^(s - mrun); 4-way partial row sums
      float p[32];
      float psa0 = 0.f, psa1 = 0.f, psa2 = 0.f, psa3 = 0.f;
#pragma unroll
      for (int r = 0; r < 16; r += 4) {
        p[r + 0] = exp2f(s0[r + 0] - mrun); psa0 += p[r + 0];
        p[r + 1] = exp2f(s0[r + 1] - mrun); psa1 += p[r + 1];
        p[r + 2] = exp2f(s0[r + 2] - mrun); psa2 += p[r + 2];
        p[r + 3] = exp2f(s0[r + 3] - mrun); psa3 += p[r + 3];
      }
#pragma unroll
      for (int r = 0; r < 16; r += 4) {
        p[16 + r + 0] = exp2f(s1[r + 0] - mrun); psa0 += p[16 + r + 0];
        p[16 + r + 1] = exp2f(s1[r + 1] - mrun); psa1 += p[16 + r + 1];
        p[16 + r + 2] = exp2f(s1[r + 2] - mrun); psa2 += p[16 + r + 2];
        p[16 + r + 3] = exp2f(s1[r + 3] - mrun); psa3 += p[16 + r + 3];
      }
      float ps = (psa0 + psa1) + (psa2 + psa3);
      ps += __shfl_xor(ps, 32);
      lrun += ps;

      unsigned int pk[16];
#pragma unroll
      for (int m = 0; m < 16; ++m) pk[m] = cvtpk(p[2 * m], p[2 * m + 1]);
#pragma unroll
      for (int base = 0; base < 16; base += 4) {
        plswap(pk[base + 0], pk[base + 2]);
        plswap(pk[base + 1], pk[base + 3]);
      }
      // PV: ctx^T[d][q] += V^T x P^T ; A=V^T frag row=d, 256B rows, +kp*128
      __builtin_amdgcn_s_setprio(1);
#pragma unroll
      for (int dt = 0; dt < 2; ++dt) {
        int row = dt * 32 + l31;
#pragma unroll
        for (int kt = 0; kt < 4; ++kt) {
          int slot = (2 * kt + h) ^ (row & 7);
          short8v vf = *(const short8v*)(Vbuf + row * 256 + kp * 128 + slot * 16);
          uint4v u = {pk[4 * kt], pk[4 * kt + 1], pk[4 * kt + 2], pk[4 * kt + 3]};
          short8v pf = __builtin_bit_cast(short8v, u);
          if (dt == 0) ctx0 = __builtin_amdgcn_mfma_f32_32x32x16_bf16(vf, pf, ctx0, 0, 0, 0);
          else         ctx1 = __builtin_amdgcn_mfma_f32_32x32x16_bf16(vf, pf, ctx1, 0, 0, 0);
        }
      }
      __builtin_amdgcn_s_setprio(0);
    }
    // counted-wait barrier AFTER compute: stage(t+1) latency hidden under compute(t)
    asm volatile("s_waitcnt vmcnt(0)" ::: "memory");
    __builtin_amdgcn_s_barrier();
    asm volatile("" ::: "memory");
  }

  // ---- split-K combine: group 1 publishes (ctx,m,l) via LDS; group 0 merges ----
  float* cws = (float*)smem + qw * 2176;   // 34 x 64 floats per q-wave (34KB total)
  if (kp == 1) {
#pragma unroll
    for (int r = 0; r < 16; ++r) {
      cws[r * 64 + lane]        = ctx0[r];
      cws[(16 + r) * 64 + lane] = ctx1[r];
    }
    cws[32 * 64 + lane] = mrun;
    cws[33 * 64 + lane] = lrun;
  }
  __syncthreads();
  if (kp == 0) {
    float pm = cws[32 * 64 + lane], pl = cws[33 * 64 + lane];
    float m  = fmaxf(mrun, pm);
    float sa = exp2f(mrun - m), sb = exp2f(pm - m);   // empty partner: sb = 0
    float L  = lrun * sa + pl * sb;
    float cf[32];
#pragma unroll
    for (int r = 0; r < 16; ++r) {
      cf[r]      = ctx0[r] * sa + cws[r * 64 + lane] * sb;
      cf[16 + r] = ctx1[r] * sa + cws[(16 + r) * 64 + lane] * sb;
    }
    const int b = bh >> 4, hcol = (bh & 15) * 64;
    unsigned short* orow = ctxb + (((size_t)(b * S_ + qg)) << 10) + hcol;
    float invL = 1.0f / L;
#pragma unroll
    for (int j = 0; j < 8; ++j) {
      uint2 w;
      w.x = cvtpk(cf[4 * j + 0] * invL, cf[4 * j + 1] * invL);
      w.y = cvtpk(cf[4 * j + 2] * invL, cf[4 * j + 3] * invL);
      // flat f=4j -> d = 32*(j>>2) + 8*(j&3) + 4*h
      *(uint2*)(orow + 32 * (j >> 2) + 8 * (j & 3) + 4 * h) = w;
    }
  }
}

// ---------------- output projection + bias + residual (fp32 y into d_out) ----------------
// Flat 256-block grid, XCD-chunked (4 M-tiles x 8 N-tiles per XCD) for A-tile
// L2 locality, same scheme as gemm_qkv.
__global__ __launch_bounds__(256) void gemm_out_kernel(
    const unsigned short* __restrict__ ctxb, const unsigned short* __restrict__ wob,
    const float* __restrict__ bo, const float* __restrict__ x, float* __restrict__ y)
{
  __shared__ __align__(16) unsigned short As[2 * 128 * 32];
  __shared__ __align__(16) unsigned short Bs[2 * 128 * 32];
  const int flat = blockIdx.x;                 // 0..255
  const int xcd = flat & 7, off = flat >> 3;   // off 0..31
  const int m0 = (xcd * 4 + (off >> 3)) * 128; // bijective over 32 M-tiles
  const int n0 = (off & 7) * 128;
  f32x4 acc[4][4];
  gemm_mainloop(ctxb, wob, D_, m0, n0, As, Bs, acc);

  const int tid = threadIdx.x, lane = tid & 63, wid = tid >> 6;
  const int wr = wid >> 1, wc = wid & 1, l15 = lane & 15, g = lane >> 4;
#pragma unroll
  for (int ni = 0; ni < 4; ++ni) {
    int n = n0 + wc * 64 + ni * 16 + l15;
    float bia = bo[n];
#pragma unroll
    for (int mi = 0; mi < 4; ++mi) {
      int mbase = m0 + wr * 64 + mi * 16 + 4 * g;
#pragma unroll
      for (int r = 0; r < 4; ++r) {
        size_t idx = ((size_t)(mbase + r) << 10) + n;
        y[idx] = acc[mi][ni][r] + bia + x[idx];
      }
    }
  }
}

// ---------------- in-place LayerNorm over rows of d_out ----------------
__global__ __launch_bounds__(256) void ln_kernel(
    float* __restrict__ y, const float* __restrict__ gw, const float* __restrict__ bw)
{
  const int row = blockIdx.x;
  float* p = y + ((size_t)row << 10);
  const int t = threadIdx.x;
  float4 v = *(const float4*)(p + t * 4);
  float s  = v.x + v.y + v.z + v.w;
  float s2 = v.x * v.x + v.y * v.y + v.z * v.z + v.w * v.w;
#pragma unroll
  for (int d = 1; d < 64; d <<= 1) { s += __shfl_xor(s, d); s2 += __shfl_xor(s2, d); }
  __shared__ float ps[4], ps2[4];
  const int lane = t & 63, wid = t >> 6;
  if (lane == 0) { ps[wid] = s; ps2[wid] = s2; }
  __syncthreads();
  s  = ps[0] + ps[1] + ps[2] + ps[3];
  s2 = ps2[0] + ps2[1] + ps2[2] + ps2[3];
  float mu  = s * (1.f / 1024.f);
  float var = s2 * (1.f / 1024.f) - mu * mu;
  float rstd = rsqrtf(var + 1e-5f);
  float4 gv = *(const float4*)(gw + t * 4);
  float4 bv = *(const float4*)(bw + t * 4);
  float4 o;
  o.x = (v.x - mu) * rstd * gv.x + bv.x;
  o.y = (v.y - mu) * rstd * gv.y + bv.y;
  o.z = (v.z - mu) * rstd * gv.z + bv.z;
  o.w = (v.w - mu) * rstd * gv.w + bv.w;
  *(float4*)(p + t * 4) = o;
}

extern "C" void kernel_launch(void* const* d_in, const int* in_sizes, int n_in,
                              void* d_out, int out_size, void* d_ws, size_t ws_size,
                              hipStream_t stream) {
  const float* x   = (const float*)d_in[0];
  const float* Wq  = (const float*)d_in[1];
  const float* bq  = (const float*)d_in[2];
  const float* Wk  = (const float*)d_in[3];
  const float* bk  = (const float*)d_in[4];
  const float* Wv  = (const float*)d_in[5];
  const float* bv  = (const float*)d_in[6];
  const float* Wo  = (const float*)d_in[7];
  const float* bo  = (const float*)d_in[8];
  const float* lng = (const float*)d_in[9];
  const float* lnb = (const float*)d_in[10];
  float* out = (float*)d_out;

  char* ws = (char*)d_ws;
  unsigned short* xb  = (unsigned short*)ws;                 ws += (size_t)MTOK * D_ * 2;
  unsigned short* wqb = (unsigned short*)ws;                 ws += (size_t)D_ * D_ * 2;
  unsigned short* wkb = (unsigned short*)ws;                 ws += (size_t)D_ * D_ * 2;
  unsigned short* wvb = (unsigned short*)ws;                 ws += (size_t)D_ * D_ * 2;
  unsigned short* wob = (unsigned short*)ws;                 ws += (size_t)D_ * D_ * 2;
  unsigned short* Qb  = (unsigned short*)ws;                 ws += (size_t)B_ * H_ * S_ * DH_ * 2;
  unsigned short* Kb  = (unsigned short*)ws;                 ws += (size_t)B_ * H_ * S_ * DH_ * 2;
  unsigned short* VTb = (unsigned short*)ws;                 ws += (size_t)B_ * H_ * DH_ * S_ * 2;
  unsigned short* ctxb = (unsigned short*)ws;                ws += (size_t)MTOK * D_ * 2;

  // one conversion launch: x (1M float4) + 4 weights (4 x 256K float4)
  cvt_all_kernel<<<(MTOK * D_ / 4 + 4 * D_ * D_ / 4) / 256, 256, 0, stream>>>(
      x, Wq, Wk, Wv, Wo, xb, wqb, wkb, wvb, wob);

  // QKV: flat 768-block grid, XCD-chunked for A-tile L2 reuse
  gemm_qkv_kernel<<<dim3(768), 256, 0, stream>>>(
      xb, wqb, wkb, wvb, bq, bk, bv, Qb, Kb, VTb);

  // flash attention: 512 x 512-thread blocks, split-K within tile, 2 blocks/CU
  attn_kernel<<<dim3((S_ / 128) * B_ * H_), 512, 0, stream>>>(Qb, Kb, VTb, ctxb);

  // out-proj: flat 256-block grid, XCD-chunked
  gemm_out_kernel<<<dim3(256), 256, 0, stream>>>(ctxb, wob, bo, x, out);

  ln_kernel<<<MTOK, 256, 0, stream>>>(out, lng, lnb);
}

// Round 15
// 122.062 us; speedup vs baseline: 1.0600x; 1.0079x over previous
//
#include <hip/hip_runtime.h>
#include <stdint.h>

#define B_   2
#define S_   2048
#define D_   1024
#define H_   16
#define DH_  64
#define MTOK (B_*S_)   // 4096

typedef __attribute__((ext_vector_type(8))) short  short8v;
typedef __attribute__((ext_vector_type(4))) float  f32x4;
typedef __attribute__((ext_vector_type(16))) float f32x16;
typedef __attribute__((ext_vector_type(4))) unsigned int uint4v;

__device__ __forceinline__ unsigned short f2bf(float f) {
  unsigned int u = __builtin_bit_cast(unsigned int, f);
  unsigned int r = (u + 0x7fffu + ((u >> 16) & 1u)) >> 16;
  return (unsigned short)r;
}

__device__ __forceinline__ f32x4 zero4() { f32x4 v = {0.f, 0.f, 0.f, 0.f}; return v; }
__device__ __forceinline__ f32x16 zero16() {
  f32x16 v;
#pragma unroll
  for (int i = 0; i < 16; ++i) v[i] = 0.f;
  return v;
}

__device__ __forceinline__ unsigned int cvtpk(float lo, float hi) {
  unsigned int d;
  asm("v_cvt_pk_bf16_f32 %0, %1, %2" : "=v"(d) : "v"(lo), "v"(hi));
  return d;
}
// after: a = [a_low | b_low], b = [a_high | b_high]
// NOTE: permlane reads bypass VALU forwarding; only safe here because operands
// come from separate compiler-scheduled statements. Do NOT feed it a value
// written by an immediately-preceding instruction in the same asm block.
__device__ __forceinline__ void plswap(unsigned int& a, unsigned int& b) {
  asm("v_permlane32_swap_b32 %0, %1" : "+v"(a), "+v"(b));
}

__device__ __forceinline__ void gload16(const void* g, void* l) {
  __builtin_amdgcn_global_load_lds(
      (const __attribute__((address_space(1))) void*)g,
      (__attribute__((address_space(3))) void*)l, 16, 0, 0);
}

// ---------------- f32 -> bf16 conversion: x + 4 weights, grid-stride ----------
// 2048 blocks x 4 items/thread (G11: cap grid ~2048, stride the rest) instead
// of 8448 one-shot blocks: better ILP per thread, fewer dispatch slots.
__global__ void cvt_all_kernel(
    const float* __restrict__ x,
    const float* __restrict__ w0, const float* __restrict__ w1,
    const float* __restrict__ w2, const float* __restrict__ w3,
    unsigned short* __restrict__ xb,
    unsigned short* __restrict__ o0, unsigned short* __restrict__ o1,
    unsigned short* __restrict__ o2, unsigned short* __restrict__ o3)
{
  const int total = MTOK * D_ / 4 + D_ * D_;     // 2097152 float4 items
  for (int i = blockIdx.x * blockDim.x + threadIdx.x; i < total;
       i += gridDim.x * blockDim.x) {
    const float* in;
    unsigned short* out;
    int off;
    if (i < MTOK * D_ / 4) {          // 1048576 x-items
      in = x; out = xb; off = i;
    } else {
      int j = i - MTOK * D_ / 4;      // 262144 items per weight
      int w = j >> 18;
      off = j & 262143;
      in  = (w == 0) ? w0 : (w == 1) ? w1 : (w == 2) ? w2 : w3;
      out = (w == 0) ? o0 : (w == 1) ? o1 : (w == 2) ? o2 : o3;
    }
    float4 v = reinterpret_cast<const float4*>(in)[off];
    ushort4 o;
    o.x = f2bf(v.x); o.y = f2bf(v.y); o.z = f2bf(v.z); o.w = f2bf(v.w);
    reinterpret_cast<ushort4*>(out)[off] = o;
  }
}

// ---------------- shared NT-GEMM mainloop: C = A(MxK) * Bt(NxK)^T ----------------
// r7 structure: BK=32 double-buffer, 2 x (8KB A + 8KB B) = 32KB -> 3 blocks/CU.
// stage(k+1) issues into the other 8KB pair while MFMA consumes k; vmcnt(0)+
// raw barrier after compute. Swizzle (row>>1)&3: bank-conflict-free (r11: 0).
// (r13 lesson: 256x128 tile -> 1.5 blocks/CU, drain unabsorbed, REGRESSED;
//  128^2 @ 3 blocks/CU is the robust optimum for this 2-barrier structure.)
__device__ __forceinline__ void stage_gemm32(
    const unsigned short* __restrict__ A, const unsigned short* __restrict__ Bt,
    int K, int m0, int n0, int k0, unsigned short* As, unsigned short* Bs, int tid)
{
#pragma unroll
  for (int it = 0; it < 2; ++it) {
    int fa = it * 256 + tid;           // 0..511: 128 rows x 4 slots of 16B
    int row = fa >> 2, slot = fa & 3;
    int gs = slot ^ ((row >> 1) & 3);
    gload16(A + (size_t)(m0 + row) * K + k0 + gs * 8, (char*)As + fa * 16);
  }
#pragma unroll
  for (int it = 0; it < 2; ++it) {
    int fa = it * 256 + tid;
    int row = fa >> 2, slot = fa & 3;
    int gs = slot ^ ((row >> 1) & 3);
    gload16(Bt + (size_t)(n0 + row) * K + k0 + gs * 8, (char*)Bs + fa * 16);
  }
}

__device__ __forceinline__ void gemm_mainloop(
    const unsigned short* __restrict__ A, const unsigned short* __restrict__ Bt,
    int K, int m0, int n0, unsigned short* As, unsigned short* Bs, f32x4 acc[4][4])
{
  const int tid = threadIdx.x;
  const int lane = tid & 63, wid = tid >> 6;
  const int wr = wid >> 1, wc = wid & 1;
  const int l15 = lane & 15, g = lane >> 4;

#pragma unroll
  for (int mi = 0; mi < 4; ++mi)
#pragma unroll
    for (int ni = 0; ni < 4; ++ni) acc[mi][ni] = zero4();

  const int nk = K >> 5;   // BK=32
  stage_gemm32(A, Bt, K, m0, n0, 0, As, Bs, tid);
  asm volatile("s_waitcnt vmcnt(0)" ::: "memory");
  __builtin_amdgcn_s_barrier();
  asm volatile("" ::: "memory");

  for (int k = 0; k < nk; ++k) {
    if (k + 1 < nk)
      stage_gemm32(A, Bt, K, m0, n0, (k + 1) << 5,
                   As + ((k + 1) & 1) * 4096, Bs + ((k + 1) & 1) * 4096, tid);
    const char* Ab = (const char*)(As + (k & 1) * 4096);
    const char* Bb = (const char*)(Bs + (k & 1) * 4096);
    short8v af[4], bfr[4];
#pragma unroll
    for (int mi = 0; mi < 4; ++mi) {
      int row = wr * 64 + mi * 16 + l15;
      int slot = g ^ ((row >> 1) & 3);
      af[mi] = *(const short8v*)(Ab + row * 64 + slot * 16);
    }
#pragma unroll
    for (int ni = 0; ni < 4; ++ni) {
      int row = wc * 64 + ni * 16 + l15;
      int slot = g ^ ((row >> 1) & 3);
      bfr[ni] = *(const short8v*)(Bb + row * 64 + slot * 16);
    }
#pragma unroll
    for (int mi = 0; mi < 4; ++mi)
#pragma unroll
      for (int ni = 0; ni < 4; ++ni)
        acc[mi][ni] = __builtin_amdgcn_mfma_f32_16x16x32_bf16(af[mi], bfr[ni], acc[mi][ni], 0, 0, 0);
    // counted-wait AFTER compute: stage(k+1) latency hidden under compute(k)
    asm volatile("s_waitcnt vmcnt(0)" ::: "memory");
    __builtin_amdgcn_s_barrier();
    asm volatile("" ::: "memory");
  }
}

// ---------------- fused QKV projection ----------------
// z=0: Q*(1/sqrt(DH)*log2e) -> [B,H,S,DH]; z=1: K -> [B,H,S,DH]; z=2: V -> [B,H,DH,S]
// Flat 768-block grid, XCD-chunked: each XCD owns 4 M-tiles x 24 N-tiles
// (n-fastest, all 3 weight slices) -> 24 consecutive co-resident blocks per
// XCD share one 256KB A-tile in that XCD's private L2 (r12 verified).
__global__ __launch_bounds__(256) void gemm_qkv_kernel(
    const unsigned short* __restrict__ xb,
    const unsigned short* __restrict__ wqb, const unsigned short* __restrict__ wkb,
    const unsigned short* __restrict__ wvb,
    const float* __restrict__ bq, const float* __restrict__ bk, const float* __restrict__ bv,
    unsigned short* __restrict__ Qb, unsigned short* __restrict__ Kb, unsigned short* __restrict__ VTb)
{
  __shared__ __align__(16) unsigned short As[2 * 128 * 32];  // 16KB
  __shared__ __align__(16) unsigned short Bs[2 * 128 * 32];  // 16KB
  const int flat = blockIdx.x;                 // 0..767
  const int xcd = flat & 7, off = flat >> 3;   // off 0..95
  const int mtile = xcd * 4 + (off / 24);      // 0..31 (bijective)
  const int ntile = off % 24;                  // 0..23
  const int z = ntile >> 3;
  const int m0 = mtile * 128, n0 = (ntile & 7) * 128;
  const unsigned short* Bt = (z == 0) ? wqb : (z == 1) ? wkb : wvb;
  const float* bias = (z == 0) ? bq : (z == 1) ? bk : bv;
  const float scl = (z == 0) ? 0.180336880f : 1.0f;  // 1/8 * log2(e)

  f32x4 acc[4][4];
  gemm_mainloop(xb, Bt, D_, m0, n0, As, Bs, acc);

  const int tid = threadIdx.x, lane = tid & 63, wid = tid >> 6;
  const int wr = wid >> 1, wc = wid & 1, l15 = lane & 15, g = lane >> 4;
#pragma unroll
  for (int ni = 0; ni < 4; ++ni) {
    int n = n0 + wc * 64 + ni * 16 + l15;
    float bia = bias[n];
    int hh = n >> 6, dh = n & 63;
#pragma unroll
    for (int mi = 0; mi < 4; ++mi) {
      int mbase = m0 + wr * 64 + mi * 16 + 4 * g;
      int b = mbase >> 11;
      int s0 = mbase & 2047;
      if (z < 2) {
        unsigned short* o = (z == 0) ? Qb : Kb;
#pragma unroll
        for (int r = 0; r < 4; ++r) {
          float v = (acc[mi][ni][r] + bia) * scl;
          o[(((size_t)(b * H_ + hh) * S_ + (s0 + r)) << 6) + dh] = f2bf(v);
        }
      } else {
        ushort4 o;
        o.x = f2bf(acc[mi][ni][0] + bia);
        o.y = f2bf(acc[mi][ni][1] + bia);
        o.z = f2bf(acc[mi][ni][2] + bia);
        o.w = f2bf(acc[mi][ni][3] + bia);
        *(ushort4*)(VTb + ((size_t)(b * H_ + hh) * DH_ + dh) * S_ + s0) = o;
      }
    }
  }
}

// ---------------- flash attention (causal, swapped-QK^T 32x32, split-K) ------
// QBLK=128, 512 threads = 8 waves: 4 q-waves x 2 KEY-GROUPS. Groups split
// WITHIN each staged 128-key tile (group kp owns keys kp*64..kp*64+63):
// LDS = 2 x 32KB = 64KB -> 2 blocks/CU (r10-r14 verified ~44us). End merge =
// associative online-softmax combine via LDS.
__device__ __forceinline__ void stage_tile128_w8(
    const unsigned short* Kh, const unsigned short* Vh, int t0, char* base, int tid)
{
  // K: 128 keys x 128B = 16KB, row=key, 8 slots of 16B, XOR-swizzled
#pragma unroll
  for (int it = 0; it < 2; ++it) {
    int fa = it * 512 + tid;
    int row = fa >> 3, slot = fa & 7, gs = slot ^ (row & 7);
    gload16(Kh + (size_t)(t0 + row) * DH_ + gs * 8, base + fa * 16);
  }
  // V^T: 64 d-rows x 256B (128 keys) = 16KB, 16 slots of 16B, low-3-bit XOR
#pragma unroll
  for (int it = 0; it < 2; ++it) {
    int fa = it * 512 + tid;
    int row = fa >> 4, slot = fa & 15;
    int gs = slot ^ (row & 7);
    gload16(Vh + (size_t)row * S_ + t0 + gs * 8, base + 16384 + fa * 16);
  }
}

__global__ __launch_bounds__(512, 4) void attn_kernel(
    const unsigned short* __restrict__ Qb, const unsigned short* __restrict__ Kb,
    const unsigned short* __restrict__ VTb, unsigned short* __restrict__ ctxb)
{
  __shared__ __align__(16) char smem[65536];  // 2 super-buffers x (K 16KB + V 16KB)
  const int tid = threadIdx.x, lane = tid & 63, wid = tid >> 6;  // wid 0..7
  const int qw = wid & 3, kp = wid >> 2;      // q-wave, key-group (sub in tile)
  const int l31 = lane & 31, h = lane >> 5;
  // XCD-aware flat-grid remap: fid%8 ~ XCD; give each XCD 4 heads (L2-fit)
  const int fid = blockIdx.x;
  const int bh = (fid & 7) * 4 + ((fid >> 3) & 3);
  const int qpos = fid >> 5;
  const int qi = (qpos < 8) ? qpos : 23 - qpos;  // pairs (p,15-p) per CU
  const int qblk = qi * 128;
  const int q0w = qblk + qw * 32;
  const int qg = q0w + l31;
  const unsigned short* Qh = Qb + (size_t)bh * S_ * DH_;
  const unsigned short* Kh = Kb + (size_t)bh * S_ * DH_;
  const unsigned short* Vh = VTb + (size_t)bh * DH_ * S_;

  // Q B-fragments: col=q=l31, k(dh) = 16*kk + 8*h + e  (Q pre-scaled in QKV epilogue)
  short8v qf[4];
#pragma unroll
  for (int kk = 0; kk < 4; ++kk)
    qf[kk] = *(const short8v*)(Qh + (size_t)qg * DH_ + kk * 16 + h * 8);

  f32x16 ctx0 = zero16(), ctx1 = zero16();
  float mrun = -3e38f, lrun = 0.f;

  const int nt = qi + 1;            // 128-key tiles 0..qi

  stage_tile128_w8(Kh, Vh, 0, smem, tid);
  asm volatile("s_waitcnt vmcnt(0)" ::: "memory");
  __builtin_amdgcn_s_barrier();
  asm volatile("" ::: "memory");

  for (int t = 0; t < nt; ++t) {
    if (t + 1 < nt) stage_tile128_w8(Kh, Vh, (t + 1) << 7, smem + (((t + 1) & 1) * 32768), tid);
    const char* Kbuf = smem + (t & 1) * 32768;
    const char* Vbuf = Kbuf + 16384;
    const int t0 = (t << 7) + (kp << 6);   // this group's 64-key subtile
    if (t0 <= q0w + 31) {                  // within this wave's causal range
      const char* Kt = Kbuf + kp * 8192;

      // QK^T swapped: s = mfma(A=K, B=Q) -> S^T[key][q], col=q=l31
      f32x16 s0 = zero16(), s1 = zero16();
      __builtin_amdgcn_s_setprio(1);
#pragma unroll
      for (int kk = 0; kk < 4; ++kk) {
        int slot = (2 * kk + h) ^ (l31 & 7);
        short8v kf0 = *(const short8v*)(Kt + l31 * 128 + slot * 16);
        short8v kf1 = *(const short8v*)(Kt + (32 + l31) * 128 + slot * 16);
        s0 = __builtin_amdgcn_mfma_f32_32x32x16_bf16(kf0, qf[kk], s0, 0, 0, 0);
        s1 = __builtin_amdgcn_mfma_f32_32x32x16_bf16(kf1, qf[kk], s1, 0, 0, 0);
      }
      __builtin_amdgcn_s_setprio(0);
      // causal mask when tile overlaps any diagonal of this wave
      if (t0 + 63 > q0w) {
#pragma unroll
        for (int r = 0; r < 16; ++r) {
          int k0i = (r & 3) + 8 * (r >> 2) + 4 * h;
          if (t0 + k0i > qg) s0[r] = -1e30f;
          if (t0 + k0i + 32 > qg) s1[r] = -1e30f;
        }
      }
      // lane-local row max: tree, then cross-half combine via shfl_xor(32)
      float tm;
      {
        float m01[8];
#pragma unroll
        for (int r = 0; r < 8; ++r)
          m01[r] = fmaxf(fmaxf(s0[r], s0[r + 8]), fmaxf(s1[r], s1[r + 8]));
        float a = fmaxf(fmaxf(m01[0], m01[1]), fmaxf(m01[2], m01[3]));
        float b = fmaxf(fmaxf(m01[4], m01[5]), fmaxf(m01[6], m01[7]));
        tm = fmaxf(a, b);
      }
      tm = fmaxf(tm, __shfl_xor(tm, 32));

      // defer-max: rescale only when tile max exceeds threshold (2^8 headroom)
      if (!__all(tm <= mrun + 8.f)) {
        float mnew = fmaxf(mrun, tm);
        float al = exp2f(mrun - mnew);
#pragma unroll
        for (int r = 0; r < 16; ++r) { ctx0[r] *= al; ctx1[r] *= al; }
        lrun *= al;
        mrun = mnew;
      }
      // P = 2^(s - mrun); 4-way partial row sums
      float p[32];
      float psa0 = 0.f, psa1 = 0.f, psa2 = 0.f, psa3 = 0.f;
#pragma unroll
      for (int r = 0; r < 16; r += 4) {
        p[r + 0] = exp2f(s0[r + 0] - mrun); psa0 += p[r + 0];
        p[r + 1] = exp2f(s0[r + 1] - mrun); psa1 += p[r + 1];
        p[r + 2] = exp2f(s0[r + 2] - mrun); psa2 += p[r + 2];
        p[r + 3] = exp2f(s0[r + 3] - mrun); psa3 += p[r + 3];
      }
#pragma unroll
      for (int r = 0; r < 16; r += 4) {
        p[16 + r + 0] = exp2f(s1[r + 0] - mrun); psa0 += p[16 + r + 0];
        p[16 + r + 1] = exp2f(s1[r + 1] - mrun); psa1 += p[16 + r + 1];
        p[16 + r + 2] = exp2f(s1[r + 2] - mrun); psa2 += p[16 + r + 2];
        p[16 + r + 3] = exp2f(s1[r + 3] - mrun); psa3 += p[16 + r + 3];
      }
      float ps = (psa0 + psa1) + (psa2 + psa3);
      ps += __shfl_xor(ps, 32);
      lrun += ps;

      unsigned int pk[16];
#pragma unroll
      for (int m = 0; m < 16; ++m) pk[m] = cvtpk(p[2 * m], p[2 * m + 1]);
#pragma unroll
      for (int base = 0; base < 16; base += 4) {
        plswap(pk[base + 0], pk[base + 2]);
        plswap(pk[base + 1], pk[base + 3]);
      }
      // PV: ctx^T[d][q] += V^T x P^T ; A=V^T frag row=d, 256B rows, +kp*128
      __builtin_amdgcn_s_setprio(1);
#pragma unroll
      for (int dt = 0; dt < 2; ++dt) {
        int row = dt * 32 + l31;
#pragma unroll
        for (int kt = 0; kt < 4; ++kt) {
          int slot = (2 * kt + h) ^ (row & 7);
          short8v vf = *(const short8v*)(Vbuf + row * 256 + kp * 128 + slot * 16);
          uint4v u = {pk[4 * kt], pk[4 * kt + 1], pk[4 * kt + 2], pk[4 * kt + 3]};
          short8v pf = __builtin_bit_cast(short8v, u);
          if (dt == 0) ctx0 = __builtin_amdgcn_mfma_f32_32x32x16_bf16(vf, pf, ctx0, 0, 0, 0);
          else         ctx1 = __builtin_amdgcn_mfma_f32_32x32x16_bf16(vf, pf, ctx1, 0, 0, 0);
        }
      }
      __builtin_amdgcn_s_setprio(0);
    }
    // counted-wait barrier AFTER compute: stage(t+1) latency hidden under compute(t)
    asm volatile("s_waitcnt vmcnt(0)" ::: "memory");
    __builtin_amdgcn_s_barrier();
    asm volatile("" ::: "memory");
  }

  // ---- split-K combine: group 1 publishes (ctx,m,l) via LDS; group 0 merges ----
  float* cws = (float*)smem + qw * 2176;   // 34 x 64 floats per q-wave (34KB total)
  if (kp == 1) {
#pragma unroll
    for (int r = 0; r < 16; ++r) {
      cws[r * 64 + lane]        = ctx0[r];
      cws[(16 + r) * 64 + lane] = ctx1[r];
    }
    cws[32 * 64 + lane] = mrun;
    cws[33 * 64 + lane] = lrun;
  }
  __syncthreads();
  if (kp == 0) {
    float pm = cws[32 * 64 + lane], pl = cws[33 * 64 + lane];
    float m  = fmaxf(mrun, pm);
    float sa = exp2f(mrun - m), sb = exp2f(pm - m);   // empty partner: sb = 0
    float L  = lrun * sa + pl * sb;
    float cf[32];
#pragma unroll
    for (int r = 0; r < 16; ++r) {
      cf[r]      = ctx0[r] * sa + cws[r * 64 + lane] * sb;
      cf[16 + r] = ctx1[r] * sa + cws[(16 + r) * 64 + lane] * sb;
    }
    const int b = bh >> 4, hcol = (bh & 15) * 64;
    unsigned short* orow = ctxb + (((size_t)(b * S_ + qg)) << 10) + hcol;
    float invL = 1.0f / L;
#pragma unroll
    for (int j = 0; j < 8; ++j) {
      uint2 w;
      w.x = cvtpk(cf[4 * j + 0] * invL, cf[4 * j + 1] * invL);
      w.y = cvtpk(cf[4 * j + 2] * invL, cf[4 * j + 3] * invL);
      // flat f=4j -> d = 32*(j>>2) + 8*(j&3) + 4*h
      *(uint2*)(orow + 32 * (j >> 2) + 8 * (j & 3) + 4 * h) = w;
    }
  }
}

// ---------------- output projection + bias + residual (fp32 y into d_out) ----------------
// Flat 256-block grid, XCD-chunked (4 M-tiles x 8 N-tiles per XCD) for A-tile
// L2 locality, same scheme as gemm_qkv.
__global__ __launch_bounds__(256) void gemm_out_kernel(
    const unsigned short* __restrict__ ctxb, const unsigned short* __restrict__ wob,
    const float* __restrict__ bo, const float* __restrict__ x, float* __restrict__ y)
{
  __shared__ __align__(16) unsigned short As[2 * 128 * 32];
  __shared__ __align__(16) unsigned short Bs[2 * 128 * 32];
  const int flat = blockIdx.x;                 // 0..255
  const int xcd = flat & 7, off = flat >> 3;   // off 0..31
  const int m0 = (xcd * 4 + (off >> 3)) * 128; // bijective over 32 M-tiles
  const int n0 = (off & 7) * 128;
  f32x4 acc[4][4];
  gemm_mainloop(ctxb, wob, D_, m0, n0, As, Bs, acc);

  const int tid = threadIdx.x, lane = tid & 63, wid = tid >> 6;
  const int wr = wid >> 1, wc = wid & 1, l15 = lane & 15, g = lane >> 4;
#pragma unroll
  for (int ni = 0; ni < 4; ++ni) {
    int n = n0 + wc * 64 + ni * 16 + l15;
    float bia = bo[n];
#pragma unroll
    for (int mi = 0; mi < 4; ++mi) {
      int mbase = m0 + wr * 64 + mi * 16 + 4 * g;
#pragma unroll
      for (int r = 0; r < 4; ++r) {
        size_t idx = ((size_t)(mbase + r) << 10) + n;
        y[idx] = acc[mi][ni][r] + bia + x[idx];
      }
    }
  }
}

// ---------------- in-place LayerNorm: ONE WAVE PER ROW ----------------
// Each wave (64 lanes x 16 floats) owns a full 1024-float row: no LDS, no
// __syncthreads, pure shfl reduce. 1024 blocks x 4 waves (was 4096 blocks
// with a cross-wave LDS reduce + barrier per row).
__global__ __launch_bounds__(256) void ln_kernel(
    float* __restrict__ y, const float* __restrict__ gw, const float* __restrict__ bw)
{
  const int lane = threadIdx.x & 63, w = threadIdx.x >> 6;
  const int row = blockIdx.x * 4 + w;
  float* p = y + ((size_t)row << 10);
  float4 v[4];
  float s = 0.f, s2 = 0.f;
#pragma unroll
  for (int i = 0; i < 4; ++i) {
    v[i] = *(const float4*)(p + i * 256 + lane * 4);
    s  += (v[i].x + v[i].y) + (v[i].z + v[i].w);
    s2 += (v[i].x * v[i].x + v[i].y * v[i].y) + (v[i].z * v[i].z + v[i].w * v[i].w);
  }
#pragma unroll
  for (int d = 1; d < 64; d <<= 1) { s += __shfl_xor(s, d); s2 += __shfl_xor(s2, d); }
  float mu  = s * (1.f / 1024.f);
  float var = s2 * (1.f / 1024.f) - mu * mu;
  float rstd = rsqrtf(var + 1e-5f);
#pragma unroll
  for (int i = 0; i < 4; ++i) {
    float4 gv = *(const float4*)(gw + i * 256 + lane * 4);
    float4 bv = *(const float4*)(bw + i * 256 + lane * 4);
    float4 o;
    o.x = (v[i].x - mu) * rstd * gv.x + bv.x;
    o.y = (v[i].y - mu) * rstd * gv.y + bv.y;
    o.z = (v[i].z - mu) * rstd * gv.z + bv.z;
    o.w = (v[i].w - mu) * rstd * gv.w + bv.w;
    *(float4*)(p + i * 256 + lane * 4) = o;
  }
}

extern "C" void kernel_launch(void* const* d_in, const int* in_sizes, int n_in,
                              void* d_out, int out_size, void* d_ws, size_t ws_size,
                              hipStream_t stream) {
  const float* x   = (const float*)d_in[0];
  const float* Wq  = (const float*)d_in[1];
  const float* bq  = (const float*)d_in[2];
  const float* Wk  = (const float*)d_in[3];
  const float* bk  = (const float*)d_in[4];
  const float* Wv  = (const float*)d_in[5];
  const float* bv  = (const float*)d_in[6];
  const float* Wo  = (const float*)d_in[7];
  const float* bo  = (const float*)d_in[8];
  const float* lng = (const float*)d_in[9];
  const float* lnb = (const float*)d_in[10];
  float* out = (float*)d_out;

  char* ws = (char*)d_ws;
  unsigned short* xb  = (unsigned short*)ws;                 ws += (size_t)MTOK * D_ * 2;
  unsigned short* wqb = (unsigned short*)ws;                 ws += (size_t)D_ * D_ * 2;
  unsigned short* wkb = (unsigned short*)ws;                 ws += (size_t)D_ * D_ * 2;
  unsigned short* wvb = (unsigned short*)ws;                 ws += (size_t)D_ * D_ * 2;
  unsigned short* wob = (unsigned short*)ws;                 ws += (size_t)D_ * D_ * 2;
  unsigned short* Qb  = (unsigned short*)ws;                 ws += (size_t)B_ * H_ * S_ * DH_ * 2;
  unsigned short* Kb  = (unsigned short*)ws;                 ws += (size_t)B_ * H_ * S_ * DH_ * 2;
  unsigned short* VTb = (unsigned short*)ws;                 ws += (size_t)B_ * H_ * DH_ * S_ * 2;
  unsigned short* ctxb = (unsigned short*)ws;                ws += (size_t)MTOK * D_ * 2;

  // conversion: grid-stride, 2048 blocks x 4 items/thread
  cvt_all_kernel<<<2048, 256, 0, stream>>>(
      x, Wq, Wk, Wv, Wo, xb, wqb, wkb, wvb, wob);

  // QKV: flat 768-block grid, XCD-chunked for A-tile L2 reuse
  gemm_qkv_kernel<<<dim3(768), 256, 0, stream>>>(
      xb, wqb, wkb, wvb, bq, bk, bv, Qb, Kb, VTb);

  // flash attention: 512 x 512-thread blocks, split-K within tile, 2 blocks/CU
  attn_kernel<<<dim3((S_ / 128) * B_ * H_), 512, 0, stream>>>(Qb, Kb, VTb, ctxb);

  // out-proj: flat 256-block grid, XCD-chunked
  gemm_out_kernel<<<dim3(256), 256, 0, stream>>>(ctxb, wob, bo, x, out);

  // LayerNorm: one wave per row, no LDS/barrier
  ln_kernel<<<MTOK / 4, 256, 0, stream>>>(out, lng, lnb);
}